// Round 10
// baseline (217.037 us; speedup 1.0000x reference)
//
#include <hip/hip_runtime.h>

#define KE_CONST 14.3996454784255f

#define P2_SHIFT 15
#define P2_CHUNK 32768            // 128 KB LDS accumulator per chunk
#define SCAN_B2  64               // blocks per chunk
#define SCAN_THR 1024             // 16 waves/block, 1 block/CU (128 KB LDS)
#define MAXC     4                // packed: 2-bit chunk + 15-bit li + 15-bit e8m7 value
#define DENSE_EPB 2048            // edges per dense block (256 thr x 8)

// ---------------- node precompute: { Zf, Zf^0.3, covrad[Z], 0 } ----------------
__global__ void zbl_node_prep(const float* __restrict__ node_attrs,
                              const int* __restrict__ atomic_numbers,
                              const float* __restrict__ covalent_radii,
                              float4* __restrict__ node_data,
                              float* __restrict__ out_zero_or_null,
                              int n_nodes, int n_elem) {
    int n = blockIdx.x * blockDim.x + threadIdx.x;
    if (n >= n_nodes) return;
    const float* row = node_attrs + (size_t)n * n_elem;
    float best = row[0];
    int bi = 0;
    for (int i = 1; i < n_elem; ++i) {
        float v = row[i];
        if (v > best) { best = v; bi = i; }
    }
    int Z = atomic_numbers[bi];
    float zf = (float)Z;
    float zp = __powf(zf, 0.3f);
    float cr = covalent_radii[Z];
    node_data[n] = make_float4(zf, zp, cr, 0.0f);
    if (out_zero_or_null) out_zero_or_null[n] = 0.0f;
}

// ---------------- per-edge math ----------------
__device__ __forceinline__ float zbl_val(float xv, const float4& du, const float4& dv,
                                         float rmax) {
    const float inv_a_pref = 1.0f / (0.4543f * 0.529f);
    float t = xv * (du.y + dv.y) * inv_a_pref;
    float phi = 0.1818f  * __expf(-3.2f    * t)
              + 0.5099f  * __expf(-0.9423f * t)
              + 0.2802f  * __expf(-0.4028f * t)
              + 0.02817f * __expf(-0.2016f * t);
    float v = KE_CONST * du.x * dv.x * phi / xv;
    float rr = xv / rmax;
    float r2 = rr * rr;
    float r6 = r2 * r2 * r2;
    float env = 1.0f - 28.0f * r6 + 48.0f * r6 * rr - 21.0f * r6 * r2;
    return 0.5f * v * env;
}

// branchless encode of the 15-bit e8m7 value field (cull applied as predicate)
__device__ __forceinline__ unsigned enc_val(float xv, const float4& du, const float4& dv) {
    float rmax = du.z + dv.z;
    float v = fmaxf(zbl_val(xv, du, dv, rmax), 0.0f);  // kill tiny negatives at r->1
    unsigned e = (__float_as_uint(v) + 0x8000u) >> 16; // bf16-style round half up
    if (e > 0x7FFFu) e = 0x7FFFu;
    return (xv < rmax) ? e : 0u;
}

__device__ __forceinline__ unsigned enc_edge(float xv, int s, int r,
                                             const float4* __restrict__ nd) {
    float4 du = nd[s];
    float4 dv = nd[r];
    return ((unsigned)r << 15) | enc_val(xv, du, dv);
}

// ---------------- pass 1: dense streaming compute -> packed u32 per edge ----------------
// Two 4-edge groups per thread from split slices so每 uint4 store is a
// wave-contiguous 1-KB burst (round-9's 8-consecutive layout had 32-B lane
// stride -> 1.56x write amplification). 16 independent gathers issued, then
// sched_barrier(0) pins them ahead of all consumption (the scheduler's
// occupancy heuristic otherwise collapses them: VGPR 36 at round 9).
__global__ __launch_bounds__(256)
void zbl_dense(const float* __restrict__ x,
               const int* __restrict__ ei,
               const float4* __restrict__ nd,
               unsigned* __restrict__ packed,
               int n_edges) {
    int tid = threadIdx.x;
    int blockBase = blockIdx.x * DENSE_EPB;
    if (blockBase + DENSE_EPB <= n_edges) {
        int a = blockBase + tid * 4;
        int b = a + (DENSE_EPB / 2);
        int4   sa = *(const int4*)(ei + a);
        int4   sb = *(const int4*)(ei + b);
        int4   ra = *(const int4*)(ei + n_edges + a);
        int4   rb = *(const int4*)(ei + n_edges + b);
        float4 xa = *(const float4*)(x + a);
        float4 xb = *(const float4*)(x + b);
        // 16 independent gathers, all issued before any consumption
        float4 du0 = nd[sa.x], du1 = nd[sa.y], du2 = nd[sa.z], du3 = nd[sa.w];
        float4 du4 = nd[sb.x], du5 = nd[sb.y], du6 = nd[sb.z], du7 = nd[sb.w];
        float4 dv0 = nd[ra.x], dv1 = nd[ra.y], dv2 = nd[ra.z], dv3 = nd[ra.w];
        float4 dv4 = nd[rb.x], dv5 = nd[rb.y], dv6 = nd[rb.z], dv7 = nd[rb.w];
        __builtin_amdgcn_sched_barrier(0);   // nothing moves across: loads stay clustered
        uint4 oa, ob;
        oa.x = ((unsigned)ra.x << 15) | enc_val(xa.x, du0, dv0);
        oa.y = ((unsigned)ra.y << 15) | enc_val(xa.y, du1, dv1);
        oa.z = ((unsigned)ra.z << 15) | enc_val(xa.z, du2, dv2);
        oa.w = ((unsigned)ra.w << 15) | enc_val(xa.w, du3, dv3);
        ob.x = ((unsigned)rb.x << 15) | enc_val(xb.x, du4, dv4);
        ob.y = ((unsigned)rb.y << 15) | enc_val(xb.y, du5, dv5);
        ob.z = ((unsigned)rb.z << 15) | enc_val(xb.z, du6, dv6);
        ob.w = ((unsigned)rb.w << 15) | enc_val(xb.w, du7, dv7);
        *(uint4*)(packed + a) = oa;   // lane-contiguous: 64 x 16 B = 1 KB burst
        *(uint4*)(packed + b) = ob;
    } else {
        int end = n_edges;
        for (int e = blockBase + tid; e < end; e += 256)
            packed[e] = enc_edge(x[e], ei[e], ei[n_edges + e], nd);
    }
}

// ---------------- pass 2: chunked scan of packed records, LDS accumulate ----------------
__global__ __launch_bounds__(SCAN_THR)
void zbl_scan(const unsigned* __restrict__ packed,
              float* __restrict__ partial,
              int n_edges) {
    unsigned c = blockIdx.x >> 6;            // SCAN_B2 = 64
    int      j = blockIdx.x & (SCAN_B2 - 1);

    __shared__ __align__(16) float acc[P2_CHUNK];
    for (int i = threadIdx.x * 4; i < P2_CHUNK; i += SCAN_THR * 4)
        *(float4*)&acc[i] = make_float4(0.f, 0.f, 0.f, 0.f);
    __syncthreads();

    long long e0 = (((long long)j * n_edges) / SCAN_B2) & ~3LL;
    long long e1 = (j == SCAN_B2 - 1) ? (long long)n_edges
                                      : ((((long long)(j + 1) * n_edges) / SCAN_B2) & ~3LL);
    long long vend = e1 & ~3LL;

    for (long long b = e0 + (long long)threadIdx.x * 4; b + 4 <= vend;
         b += (long long)SCAN_THR * 4) {
        uint4 p = *(const uint4*)(packed + b);
        if ((p.x >> 30) == c) atomicAdd(&acc[(p.x >> 15) & (P2_CHUNK - 1)],
                                        __uint_as_float((p.x & 0x7FFFu) << 16));
        if ((p.y >> 30) == c) atomicAdd(&acc[(p.y >> 15) & (P2_CHUNK - 1)],
                                        __uint_as_float((p.y & 0x7FFFu) << 16));
        if ((p.z >> 30) == c) atomicAdd(&acc[(p.z >> 15) & (P2_CHUNK - 1)],
                                        __uint_as_float((p.z & 0x7FFFu) << 16));
        if ((p.w >> 30) == c) atomicAdd(&acc[(p.w >> 15) & (P2_CHUNK - 1)],
                                        __uint_as_float((p.w & 0x7FFFu) << 16));
    }
    for (long long e = vend + threadIdx.x; e < e1; e += SCAN_THR) {
        unsigned w = packed[e];
        if ((w >> 30) == c) atomicAdd(&acc[(w >> 15) & (P2_CHUNK - 1)],
                                      __uint_as_float((w & 0x7FFFu) << 16));
    }

    __syncthreads();
    float* pp = partial + (size_t)blockIdx.x * P2_CHUNK;
    for (int i = threadIdx.x * 4; i < P2_CHUNK; i += SCAN_THR * 4)
        *(float4*)(pp + i) = *(const float4*)&acc[i];
}

// ---------------- pass 3: reduce SCAN_B2 partials per node, overwrite out ----------------
__global__ void zbl_reduce(const float* __restrict__ partial,
                           float* __restrict__ out,
                           int n_nodes) {
    int i = blockIdx.x * blockDim.x + threadIdx.x;
    if (i >= n_nodes) return;
    int c  = i >> P2_SHIFT;
    int li = i & (P2_CHUNK - 1);
    const float* p = partial + ((size_t)c * SCAN_B2) * P2_CHUNK + li;
    float s0 = 0.f, s1 = 0.f, s2 = 0.f, s3 = 0.f;
    #pragma unroll
    for (int j = 0; j < SCAN_B2; j += 4) {
        s0 += p[(size_t)(j + 0) * P2_CHUNK];
        s1 += p[(size_t)(j + 1) * P2_CHUNK];
        s2 += p[(size_t)(j + 2) * P2_CHUNK];
        s3 += p[(size_t)(j + 3) * P2_CHUNK];
    }
    out[i] = (s0 + s1) + (s2 + s3);
}

// ---------------- fallback: direct device atomics ----------------
__global__ void zbl_edge_atomic(const float* __restrict__ x,
                                const int* __restrict__ edge_index,
                                const float4* __restrict__ node_data,
                                float* __restrict__ out,
                                int n_edges) {
    int e = blockIdx.x * blockDim.x + threadIdx.x;
    if (e >= n_edges) return;
    int snd = edge_index[e];
    int r = edge_index[n_edges + e];
    float xv = x[e];
    float4 du = node_data[snd];
    float4 dv = node_data[r];
    float rmax = du.z + dv.z;
    if (xv >= rmax) return;
    atomicAdd(&out[r], zbl_val(xv, du, dv, rmax));
}

extern "C" void kernel_launch(void* const* d_in, const int* in_sizes, int n_in,
                              void* d_out, int out_size, void* d_ws, size_t ws_size,
                              hipStream_t stream) {
    const float* x              = (const float*)d_in[0];
    const float* node_attrs     = (const float*)d_in[1];
    const int*   edge_index     = (const int*)d_in[2];
    const int*   atomic_numbers = (const int*)d_in[3];
    const float* covalent_radii = (const float*)d_in[4];
    float* out = (float*)d_out;

    int n_edges = in_sizes[0];
    int n_elem  = in_sizes[3];
    int n_nodes = in_sizes[1] / n_elem;

    float4* node_data = (float4*)d_ws;
    size_t nd_bytes = (((size_t)n_nodes * sizeof(float4)) + 255) & ~(size_t)255;

    int C = (n_nodes + P2_CHUNK - 1) >> P2_SHIFT;
    size_t packed_bytes = (((size_t)n_edges * sizeof(unsigned)) + 255) & ~(size_t)255;
    size_t part_bytes   = (size_t)C * SCAN_B2 * P2_CHUNK * sizeof(float);
    bool fast = (C >= 1) && (C <= MAXC) && (n_nodes <= (1 << 17)) &&
                (ws_size >= nd_bytes + packed_bytes + part_bytes);

    if (fast) {
        unsigned* packed = (unsigned*)((char*)d_ws + nd_bytes);
        float*    part   = (float*)((char*)d_ws + nd_bytes + packed_bytes);

        zbl_node_prep<<<(n_nodes + 255) / 256, 256, 0, stream>>>(
            node_attrs, atomic_numbers, covalent_radii, node_data,
            nullptr, n_nodes, n_elem);

        zbl_dense<<<(n_edges + DENSE_EPB - 1) / DENSE_EPB, 256, 0, stream>>>(
            x, edge_index, node_data, packed, n_edges);

        zbl_scan<<<C * SCAN_B2, SCAN_THR, 0, stream>>>(packed, part, n_edges);

        zbl_reduce<<<(n_nodes + 255) / 256, 256, 0, stream>>>(part, out, n_nodes);
        return;
    }

    // fallback: plain device atomics
    zbl_node_prep<<<(n_nodes + 255) / 256, 256, 0, stream>>>(
        node_attrs, atomic_numbers, covalent_radii, node_data,
        out, n_nodes, n_elem);
    zbl_edge_atomic<<<(n_edges + 255) / 256, 256, 0, stream>>>(
        x, edge_index, node_data, out, n_edges);
}

// Round 11
// 202.473 us; speedup vs baseline: 1.0719x; 1.0719x over previous
//
#include <hip/hip_runtime.h>

#define KE_CONST 14.3996454784255f

#define P2_SHIFT 15
#define P2_CHUNK 32768            // 128 KB LDS accumulator per chunk
#define SCAN_B2  64               // blocks per chunk
#define SCAN_THR 1024             // 16 waves/block, 1 block/CU (128 KB LDS)
#define MAXC     4                // packed: 2-bit chunk + 15-bit li + 15-bit e8m7 value
#define MAXE     16               // max element types for fast path (pair table <= 256)

// ---------------- fast-path prep A: per-node element id (argmax over attrs) ----------------
__global__ void zbl_prep_elem(const float* __restrict__ node_attrs,
                              unsigned char* __restrict__ elem,
                              int n_nodes, int n_elem) {
    int n = blockIdx.x * blockDim.x + threadIdx.x;
    if (n >= n_nodes) return;
    const float* row = node_attrs + (size_t)n * n_elem;
    float best = row[0];
    int bi = 0;
    for (int i = 1; i < n_elem; ++i) {
        float v = row[i];
        if (v > best) { best = v; bi = i; }
    }
    elem[n] = (unsigned char)bi;
}

// ---------------- fast-path prep B: 100-entry pair table ----------------
// pair_tab[eu*n_elem+ev] = { 1/a, 0.5*KE*Zu*Zv, rmax, 1/rmax }
__global__ void zbl_prep_pairs(const int* __restrict__ atomic_numbers,
                               const float* __restrict__ covalent_radii,
                               float4* __restrict__ pair_tab,
                               int n_elem) {
    int t = threadIdx.x;
    int np = n_elem * n_elem;
    if (t >= np) return;
    int eu = t / n_elem;
    int ev = t - eu * n_elem;
    int Zu = atomic_numbers[eu];
    int Zv = atomic_numbers[ev];
    float zu = (float)Zu, zv = (float)Zv;
    float inv_a = (__powf(zu, 0.3f) + __powf(zv, 0.3f)) * (1.0f / (0.4543f * 0.529f));
    float kezz  = 0.5f * KE_CONST * zu * zv;
    float rmax  = covalent_radii[Zu] + covalent_radii[Zv];
    pair_tab[t] = make_float4(inv_a, kezz, rmax, 1.0f / rmax);
}

// ---------------- per-edge math from pair-table entry ----------------
__device__ __forceinline__ unsigned enc_val_p(float xv, const float4& pt) {
    float t = xv * pt.x;
    float phi = 0.1818f  * __expf(-3.2f    * t)
              + 0.5099f  * __expf(-0.9423f * t)
              + 0.2802f  * __expf(-0.4028f * t)
              + 0.02817f * __expf(-0.2016f * t);
    float rr = xv * pt.w;
    float r2 = rr * rr;
    float r6 = r2 * r2 * r2;
    float env = 1.0f - 28.0f * r6 + 48.0f * r6 * rr - 21.0f * r6 * r2;
    float val = fmaxf(pt.y * phi / xv * env, 0.0f);   // clamp r->1 cancellation negatives
    unsigned e = (__float_as_uint(val) + 0x8000u) >> 16;  // e8m7 round half up
    if (e > 0x7FFFu) e = 0x7FFFu;
    return (xv < pt.z) ? e : 0u;
}

// ---------------- pass 1: dense streaming compute -> packed u32 per edge ----------------
// Node-pair physics collapsed to a 100-entry LDS table; per-edge gathers are
// 2 BYTES from a 100 KB elem table (L1/L2-hot) instead of 2x16B from 1.6 MB
// (L2-latency-bound at rounds 8-10, pinned ~72-76 us).
__global__ __launch_bounds__(256)
void zbl_dense(const float* __restrict__ x,
               const int* __restrict__ ei,
               const unsigned char* __restrict__ elem,
               const float4* __restrict__ pair_tab,
               unsigned* __restrict__ packed,
               int n_edges, int n_elem) {
    __shared__ float4 pt[MAXE * MAXE];
    int np = n_elem * n_elem;
    for (int i = threadIdx.x; i < np; i += 256) pt[i] = pair_tab[i];
    __syncthreads();

    int t = blockIdx.x * blockDim.x + threadIdx.x;
    int base = t * 4;
    if (base + 4 <= n_edges) {
        int4   s4 = *(const int4*)(ei + base);
        int4   r4 = *(const int4*)(ei + n_edges + base);
        float4 x4 = *(const float4*)(x + base);
        // 8 independent byte gathers from the hot 100 KB table
        unsigned es0 = elem[s4.x], es1 = elem[s4.y], es2 = elem[s4.z], es3 = elem[s4.w];
        unsigned er0 = elem[r4.x], er1 = elem[r4.y], er2 = elem[r4.z], er3 = elem[r4.w];
        float4 p0 = pt[es0 * n_elem + er0];
        float4 p1 = pt[es1 * n_elem + er1];
        float4 p2 = pt[es2 * n_elem + er2];
        float4 p3 = pt[es3 * n_elem + er3];
        uint4 o;
        o.x = ((unsigned)r4.x << 15) | enc_val_p(x4.x, p0);
        o.y = ((unsigned)r4.y << 15) | enc_val_p(x4.y, p1);
        o.z = ((unsigned)r4.z << 15) | enc_val_p(x4.z, p2);
        o.w = ((unsigned)r4.w << 15) | enc_val_p(x4.w, p3);
        *(uint4*)(packed + base) = o;   // lane-contiguous 1 KB burst
    } else {
        for (int e = base; e < n_edges; ++e) {
            unsigned es = elem[ei[e]];
            unsigned er = elem[ei[n_edges + e]];
            int r = ei[n_edges + e];
            packed[e] = ((unsigned)r << 15) | enc_val_p(x[e], pt[es * n_elem + er]);
        }
    }
}

// ---------------- pass 2: chunked scan of packed records, LDS accumulate ----------------
__global__ __launch_bounds__(SCAN_THR)
void zbl_scan(const unsigned* __restrict__ packed,
              float* __restrict__ partial,
              int n_edges) {
    unsigned c = blockIdx.x >> 6;            // SCAN_B2 = 64
    int      j = blockIdx.x & (SCAN_B2 - 1);

    __shared__ __align__(16) float acc[P2_CHUNK];
    for (int i = threadIdx.x * 4; i < P2_CHUNK; i += SCAN_THR * 4)
        *(float4*)&acc[i] = make_float4(0.f, 0.f, 0.f, 0.f);
    __syncthreads();

    long long e0 = (((long long)j * n_edges) / SCAN_B2) & ~3LL;
    long long e1 = (j == SCAN_B2 - 1) ? (long long)n_edges
                                      : ((((long long)(j + 1) * n_edges) / SCAN_B2) & ~3LL);
    long long vend = e1 & ~3LL;

    for (long long b = e0 + (long long)threadIdx.x * 4; b + 4 <= vend;
         b += (long long)SCAN_THR * 4) {
        uint4 p = *(const uint4*)(packed + b);
        if ((p.x >> 30) == c) atomicAdd(&acc[(p.x >> 15) & (P2_CHUNK - 1)],
                                        __uint_as_float((p.x & 0x7FFFu) << 16));
        if ((p.y >> 30) == c) atomicAdd(&acc[(p.y >> 15) & (P2_CHUNK - 1)],
                                        __uint_as_float((p.y & 0x7FFFu) << 16));
        if ((p.z >> 30) == c) atomicAdd(&acc[(p.z >> 15) & (P2_CHUNK - 1)],
                                        __uint_as_float((p.z & 0x7FFFu) << 16));
        if ((p.w >> 30) == c) atomicAdd(&acc[(p.w >> 15) & (P2_CHUNK - 1)],
                                        __uint_as_float((p.w & 0x7FFFu) << 16));
    }
    for (long long e = vend + threadIdx.x; e < e1; e += SCAN_THR) {
        unsigned w = packed[e];
        if ((w >> 30) == c) atomicAdd(&acc[(w >> 15) & (P2_CHUNK - 1)],
                                      __uint_as_float((w & 0x7FFFu) << 16));
    }

    __syncthreads();
    float* pp = partial + (size_t)blockIdx.x * P2_CHUNK;
    for (int i = threadIdx.x * 4; i < P2_CHUNK; i += SCAN_THR * 4)
        *(float4*)(pp + i) = *(const float4*)&acc[i];
}

// ---------------- pass 3: reduce SCAN_B2 partials per node, overwrite out ----------------
__global__ void zbl_reduce(const float* __restrict__ partial,
                           float* __restrict__ out,
                           int n_nodes) {
    int i = blockIdx.x * blockDim.x + threadIdx.x;
    if (i >= n_nodes) return;
    int c  = i >> P2_SHIFT;
    int li = i & (P2_CHUNK - 1);
    const float* p = partial + ((size_t)c * SCAN_B2) * P2_CHUNK + li;
    float s0 = 0.f, s1 = 0.f, s2 = 0.f, s3 = 0.f;
    #pragma unroll
    for (int j = 0; j < SCAN_B2; j += 4) {
        s0 += p[(size_t)(j + 0) * P2_CHUNK];
        s1 += p[(size_t)(j + 1) * P2_CHUNK];
        s2 += p[(size_t)(j + 2) * P2_CHUNK];
        s3 += p[(size_t)(j + 3) * P2_CHUNK];
    }
    out[i] = (s0 + s1) + (s2 + s3);
}

// ================= fallback path: node float4 table + direct device atomics =================
__global__ void zbl_node_prep(const float* __restrict__ node_attrs,
                              const int* __restrict__ atomic_numbers,
                              const float* __restrict__ covalent_radii,
                              float4* __restrict__ node_data,
                              float* __restrict__ out_zero,
                              int n_nodes, int n_elem) {
    int n = blockIdx.x * blockDim.x + threadIdx.x;
    if (n >= n_nodes) return;
    const float* row = node_attrs + (size_t)n * n_elem;
    float best = row[0];
    int bi = 0;
    for (int i = 1; i < n_elem; ++i) {
        float v = row[i];
        if (v > best) { best = v; bi = i; }
    }
    int Z = atomic_numbers[bi];
    float zf = (float)Z;
    node_data[n] = make_float4(zf, __powf(zf, 0.3f), covalent_radii[Z], 0.0f);
    out_zero[n] = 0.0f;
}

__global__ void zbl_edge_atomic(const float* __restrict__ x,
                                const int* __restrict__ edge_index,
                                const float4* __restrict__ node_data,
                                float* __restrict__ out,
                                int n_edges) {
    int e = blockIdx.x * blockDim.x + threadIdx.x;
    if (e >= n_edges) return;
    int snd = edge_index[e];
    int r = edge_index[n_edges + e];
    float xv = x[e];
    float4 du = node_data[snd];
    float4 dv = node_data[r];
    float rmax = du.z + dv.z;
    if (xv >= rmax) return;
    const float inv_a_pref = 1.0f / (0.4543f * 0.529f);
    float t = xv * (du.y + dv.y) * inv_a_pref;
    float phi = 0.1818f  * __expf(-3.2f    * t)
              + 0.5099f  * __expf(-0.9423f * t)
              + 0.2802f  * __expf(-0.4028f * t)
              + 0.02817f * __expf(-0.2016f * t);
    float v = KE_CONST * du.x * dv.x * phi / xv;
    float rr = xv / rmax;
    float r2 = rr * rr;
    float r6 = r2 * r2 * r2;
    float env = 1.0f - 28.0f * r6 + 48.0f * r6 * rr - 21.0f * r6 * r2;
    atomicAdd(&out[r], 0.5f * v * env);
}

extern "C" void kernel_launch(void* const* d_in, const int* in_sizes, int n_in,
                              void* d_out, int out_size, void* d_ws, size_t ws_size,
                              hipStream_t stream) {
    const float* x              = (const float*)d_in[0];
    const float* node_attrs     = (const float*)d_in[1];
    const int*   edge_index     = (const int*)d_in[2];
    const int*   atomic_numbers = (const int*)d_in[3];
    const float* covalent_radii = (const float*)d_in[4];
    float* out = (float*)d_out;

    int n_edges = in_sizes[0];
    int n_elem  = in_sizes[3];
    int n_nodes = in_sizes[1] / n_elem;

    int C = (n_nodes + P2_CHUNK - 1) >> P2_SHIFT;
    size_t elem_bytes   = (((size_t)n_nodes) + 255) & ~(size_t)255;
    size_t pair_bytes   = ((size_t)MAXE * MAXE * sizeof(float4) + 255) & ~(size_t)255;
    size_t packed_bytes = (((size_t)n_edges * sizeof(unsigned)) + 255) & ~(size_t)255;
    size_t part_bytes   = (size_t)C * SCAN_B2 * P2_CHUNK * sizeof(float);
    bool fast = (C >= 1) && (C <= MAXC) && (n_nodes <= (1 << 17)) &&
                (n_elem >= 1) && (n_elem <= MAXE) && ((n_edges & 3) == 0) &&
                (ws_size >= elem_bytes + pair_bytes + packed_bytes + part_bytes);

    if (fast) {
        unsigned char* elem     = (unsigned char*)d_ws;
        float4*        pair_tab = (float4*)((char*)d_ws + elem_bytes);
        unsigned*      packed   = (unsigned*)((char*)d_ws + elem_bytes + pair_bytes);
        float*         part     = (float*)((char*)d_ws + elem_bytes + pair_bytes + packed_bytes);

        zbl_prep_elem<<<(n_nodes + 255) / 256, 256, 0, stream>>>(
            node_attrs, elem, n_nodes, n_elem);
        zbl_prep_pairs<<<1, 256, 0, stream>>>(
            atomic_numbers, covalent_radii, pair_tab, n_elem);

        zbl_dense<<<(n_edges / 4 + 255) / 256, 256, 0, stream>>>(
            x, edge_index, elem, pair_tab, packed, n_edges, n_elem);

        zbl_scan<<<C * SCAN_B2, SCAN_THR, 0, stream>>>(packed, part, n_edges);

        zbl_reduce<<<(n_nodes + 255) / 256, 256, 0, stream>>>(part, out, n_nodes);
        return;
    }

    // fallback: node table + plain device atomics
    float4* node_data = (float4*)d_ws;
    zbl_node_prep<<<(n_nodes + 255) / 256, 256, 0, stream>>>(
        node_attrs, atomic_numbers, covalent_radii, node_data,
        out, n_nodes, n_elem);
    zbl_edge_atomic<<<(n_edges + 255) / 256, 256, 0, stream>>>(
        x, edge_index, node_data, out, n_edges);
}